// Round 5
// baseline (585.849 us; speedup 1.0000x reference)
//
#include <hip/hip_runtime.h>
#include <math.h>

#define P_TOT 4096
#define IN_DIM 1024
#define DDIM 24
#define MKEYS 4096
#define HDIM 256
#define CCENT 256
#define KTOP 32

typedef short bf16x8 __attribute__((ext_vector_type(8)));
typedef float f32x4 __attribute__((ext_vector_type(4)));

// ---- workspace layout (float units) ----
static const size_t o_Yq      = 0;                                   // 4096x72 f32
static const size_t o_Yp      = o_Yq + (size_t)P_TOT*72;             // 4096x256 f32
static const size_t o_q       = o_Yp + (size_t)P_TOT*256;            // 4096x24 f32
static const size_t o_qq      = o_q + (size_t)P_TOT*DDIM;            // 4096 f32
static const size_t o_KF      = o_qq + P_TOT;                        // 4096x512 f32
static const size_t o_keynorm = o_KF + (size_t)P_TOT*512;            // 4096
static const size_t o_centnorm= o_keynorm + MKEYS;                   // 256
static const size_t o_coef    = o_centnorm + CCENT;                  // 64
static const size_t o_vread   = o_coef + 64;                         // 4096x72 f32
static const size_t o_keysT   = o_vread + (size_t)P_TOT*72;          // 24x4096 f32
static const size_t o_sel     = o_keysT + (size_t)DDIM*MKEYS;        // 256 int
static const size_t o_mask    = o_sel + 256;                         // 4096 int
static const size_t o_count   = o_mask + MKEYS;                      // 64 int
static const size_t o_A3      = o_count + 64;                        // 4096x2048 bf16 [xh|xl]
static const size_t o_W2cat   = o_A3 + (size_t)P_TOT*2048/2;         // 256x2048 bf16 [wh|wh]
static const size_t o_KCbf    = o_W2cat + (size_t)256*2048/2;        // 4096x512 bf16
static const size_t o_TTT     = o_KCbf + (size_t)P_TOT*512/2;        // 512x512 bf16
static const size_t o_Xcatbf  = o_TTT + (size_t)512*512/2;           // 4096x512 bf16
static const size_t o_W2T     = o_Xcatbf + (size_t)P_TOT*512/2;      // 72x512 bf16
static const size_t o_membf   = o_W2T + (size_t)72*512/2;            // 4096x96 bf16
static const size_t o_WoutT   = o_membf + (size_t)P_TOT*96/2;        // 1024x96 bf16

__device__ __forceinline__ float gelu_f(float x){
    return 0.5f * x * (1.0f + erff(x * 0.70710678118654752f));
}
__device__ __forceinline__ ushort f2bf(float f){
    union { float f; unsigned u; } a; a.f = f;
    unsigned u = a.u;
    return (ushort)((u + 0x7fffu + ((u >> 16) & 1u)) >> 16);
}
__device__ __forceinline__ float bf2f(ushort b){
    union { unsigned u; float f; } a; a.u = ((unsigned)b) << 16;
    return a.f;
}

#define TWO_PI_F 6.2831853071795864769f
#define STEP_F   0.024543692606170262f   // 2*pi/256

// ---------------- setup kernels ----------------
__global__ void setup_small(const float* __restrict__ fw, const float* __restrict__ cent,
                            float* __restrict__ coefp, float* __restrict__ centnorm,
                            int* __restrict__ sel, int* __restrict__ count)
{
    int t = threadIdx.x;
    if (t == 0){
        float m = fmaxf(fmaxf(fw[0],fw[1]),fmaxf(fw[2],fw[3]));
        float e0=expf(fw[0]-m), e1=expf(fw[1]-m), e2=expf(fw[2]-m), e3=expf(fw[3]-m);
        float s = e0+e1+e2+e3;
        *coefp = (e0 + e1*0.25f + e2*0.0625f + e3*0.015625f) / s;
        *count = 0;
    }
    if (t < CCENT){
        sel[t] = 0;
        float s = 0.f;
        #pragma unroll
        for (int d=0; d<DDIM; ++d){ float v = cent[t*DDIM+d]; s += v*v; }
        centnorm[t] = s;
    }
}

__global__ void key_setup(const float* __restrict__ keys, float* __restrict__ keynorm,
                          float* __restrict__ keysT)
{
    int m = blockIdx.x*256 + threadIdx.x;
    float s = 0.f;
    #pragma unroll
    for (int d=0; d<DDIM; ++d){
        float v = keys[m*DDIM+d]; s += v*v;
        keysT[(size_t)d*MKEYS + m] = v;
    }
    keynorm[m] = s;
}

// x -> hi/lo split bf16: A3[p] = [xh(1024) | xl(1024)]
__global__ void conv_x2(const float* __restrict__ x, ushort* __restrict__ A3)
{
    int i = blockIdx.x*256 + threadIdx.x;
    int p = i >> 8, j = (i & 255) * 4;
    float4 v = *(const float4*)&x[(size_t)p*IN_DIM + j];
    ushort4 hi, lo;
    hi.x=f2bf(v.x); lo.x=f2bf(v.x - bf2f(hi.x));
    hi.y=f2bf(v.y); lo.y=f2bf(v.y - bf2f(hi.y));
    hi.z=f2bf(v.z); lo.z=f2bf(v.z - bf2f(hi.z));
    hi.w=f2bf(v.w); lo.w=f2bf(v.w - bf2f(hi.w));
    *(ushort4*)&A3[(size_t)p*2048 + j]        = hi;
    *(ushort4*)&A3[(size_t)p*2048 + 1024 + j] = lo;
}

// W2cat[n] = [wh(1024) | wh(1024)], n = phase col (Wk col)
__global__ void conv_W2cat(const float* __restrict__ Wk, ushort* __restrict__ W2cat)
{
    int idx = blockIdx.x*256 + threadIdx.x;    // 256*2048
    int n = idx >> 11, k = idx & 2047;
    int kk = k & 1023;
    W2cat[idx] = f2bf(Wk[kk*256 + n]);
}

__global__ void conv_WoutT(const float* __restrict__ Wout, ushort* __restrict__ WoutT)
{
    int idx = blockIdx.x*256 + threadIdx.x;    // 1024*96
    int n = idx / 96, k = idx - n*96;
    float v = (k < 72) ? Wout[(size_t)k*IN_DIM + n] : 0.f;
    WoutT[idx] = f2bf(v);
}

// forward-DFT + entangle folded, transposed bf16: TTT[c][r]
__global__ void build_TTT(const float* __restrict__ ek, ushort* __restrict__ TTT)
{
    int idx = blockIdx.x*256 + threadIdx.x;   // 512*512, idx = c*512 + r
    int c = idx >> 9, r = idx & 511;
    int n = c & 255, h = r & 255;
    float th = (float)((n*h) & 255) * STEP_F - ek[n];
    float sn, cs; sincosf(th, &sn, &cs);
    float v;
    if (r < 256) v = (c < 256) ? cs : -sn;
    else         v = (c < 256) ? sn : cs;
    TTT[idx] = f2bf(v);
}

// inverse-DFT folded into W_read, transposed bf16: W2T[j][k]
__global__ void build_W2T(const float* __restrict__ Wr, ushort* __restrict__ W2T)
{
    __shared__ float tab[256];
    int t = threadIdx.x;
    tab[t] = cosf((float)t * STEP_F);
    __syncthreads();
    int idx = blockIdx.x*256 + t;   // 72*512
    if (idx >= 72*512) return;
    int j = idx >> 9, k = idx & 511;
    int n = k & 255;
    float acc = 0.f;
    for (int h=0; h<256; ++h){
        int xdx = (n*h) & 255;
        float c = tab[xdx], s = tab[(xdx+192) & 255];
        float w1 = Wr[h*72 + j], w2 = Wr[(256+h)*72 + j];
        acc += (k < 256) ? (c*w1 + s*w2) : (c*w2 - s*w1);
    }
    W2T[idx] = f2bf(acc * (1.f/256.f));
}

// ---------------- Yq: fp32 VALU GEMM, 4096x72, K=1024, sequential-k ----------------
__global__ __launch_bounds__(256) void yq_gemm(
    const float* __restrict__ x, const float* __restrict__ W_in,
    const float* __restrict__ b_in, float* __restrict__ Yq)
{
    __shared__ float xs[4][1024];
    const int t = threadIdx.x;
    const int p0 = blockIdx.x * 4;
    #pragma unroll
    for (int i=0;i<4;++i){
        int s = t + 256*i;              // float4 slot 0..1023
        int r = s >> 8, c4 = s & 255;
        *(float4*)&xs[r][c4*4] = *(const float4*)&x[(size_t)(p0+r)*IN_DIM + c4*4];
    }
    __syncthreads();
    const int r = t >> 6, j = t & 63;
    const float* xr = xs[r];
    float acc0 = 0.f, acc1 = 0.f;
    #pragma unroll 8
    for (int k=0;k<1024;++k){
        float xv = xr[k];
        acc0 = fmaf(xv, W_in[k*72 + j], acc0);
        if (j < 8) acc1 = fmaf(xv, W_in[k*72 + 64 + j], acc1);
    }
    Yq[(size_t)(p0+r)*72 + j] = acc0 + b_in[j];
    if (j < 8) Yq[(size_t)(p0+r)*72 + 64 + j] = acc1 + b_in[64+j];
}

// ---------------- bf16 MFMA GEMM ----------------
__global__ __launch_bounds__(256) void gemm_bf16(
    const ushort* __restrict__ A, const ushort* __restrict__ BT,
    float* __restrict__ C, const float* __restrict__ bias,
    const float* __restrict__ addm, ushort* __restrict__ Cbf,
    int M, int N, int Kloop, int Nb, int NbfPad, int lda, int ldb, int aMask)
{
    __shared__ __align__(16) ushort As[64][40];
    __shared__ __align__(16) ushort Bs[64][40];
    const int tid = threadIdx.x;
    const int lane = tid & 63, wid = tid >> 6;
    const int wm = wid >> 1, wn = wid & 1;
    const int m0 = blockIdx.y * 64, n0 = blockIdx.x * 64;
    const int fr = lane & 15, fc = lane >> 4;
    const int srow = tid >> 2, schunk = (tid & 3) * 8;
    f32x4 acc[2][2] = {};
    for (int k0 = 0; k0 < Kloop; k0 += 32){
        int ka = (k0 + schunk) & aMask;
        *(bf16x8*)&As[srow][schunk] =
            *(const bf16x8*)&A[(size_t)(m0 + srow) * lda + ka];
        {
            int n = n0 + srow;
            bf16x8 v = {};
            if (n < Nb) v = *(const bf16x8*)&BT[(size_t)n * ldb + k0 + schunk];
            *(bf16x8*)&Bs[srow][schunk] = v;
        }
        __syncthreads();
        bf16x8 a0 = *(bf16x8*)&As[wm*32 + fr][fc*8];
        bf16x8 a1 = *(bf16x8*)&As[wm*32 + 16 + fr][fc*8];
        bf16x8 b0 = *(bf16x8*)&Bs[wn*32 + fr][fc*8];
        bf16x8 b1 = *(bf16x8*)&Bs[wn*32 + 16 + fr][fc*8];
        acc[0][0] = __builtin_amdgcn_mfma_f32_16x16x32_bf16(a0, b0, acc[0][0], 0,0,0);
        acc[0][1] = __builtin_amdgcn_mfma_f32_16x16x32_bf16(a0, b1, acc[0][1], 0,0,0);
        acc[1][0] = __builtin_amdgcn_mfma_f32_16x16x32_bf16(a1, b0, acc[1][0], 0,0,0);
        acc[1][1] = __builtin_amdgcn_mfma_f32_16x16x32_bf16(a1, b1, acc[1][1], 0,0,0);
        __syncthreads();
    }
    #pragma unroll
    for (int mi=0; mi<2; ++mi){
        #pragma unroll
        for (int ni=0; ni<2; ++ni){
            #pragma unroll
            for (int rr=0; rr<4; ++rr){
                int gm = m0 + wm*32 + mi*16 + fc*4 + rr;
                int gn = n0 + wn*32 + ni*16 + fr;
                float v = acc[mi][ni][rr];
                if (gn < N){
                    if (bias) v += bias[gn];
                    if (addm) v += addm[(size_t)gm*N + gn];
                    if (C) C[(size_t)gm*N + gn] = v;
                } else v = 0.f;
                if (Cbf && gn < NbfPad)
                    Cbf[(size_t)gm*NbfPad + gn] = f2bf(v);
            }
        }
    }
}

// ---------------- LN+GELU+ricci (from Yq) + phase (from Yp) ----------------
__global__ __launch_bounds__(256) void post_proj(
    const float* __restrict__ Yq, const float* __restrict__ Yp,
    const float* __restrict__ ricci,
    float* __restrict__ q, float* __restrict__ qq, ushort* __restrict__ KCbf)
{
    int wave = threadIdx.x >> 6, lane = threadIdx.x & 63;
    int p = blockIdx.x*4 + wave;
    __shared__ float zsh[4][72];
    __shared__ float zbsh[4][24];
    const float* Yr = Yq + (size_t)p*72;
    float v1 = Yr[lane];
    float v2 = (lane < 8) ? Yr[64+lane] : 0.f;
    float s = v1 + v2, s2 = v1*v1 + v2*v2;
    #pragma unroll
    for (int off=32; off; off>>=1){ s += __shfl_xor(s,off); s2 += __shfl_xor(s2,off); }
    float mean = s * (1.f/72.f);
    float var  = s2 * (1.f/72.f) - mean*mean;
    float rstd = rsqrtf(var + 1e-5f);
    zsh[wave][lane] = gelu_f((v1-mean)*rstd);
    if (lane < 8) zsh[wave][64+lane] = gelu_f((v2-mean)*rstd);
    __syncthreads();
    if (lane < 24){
        float zb = (zsh[wave][lane*3] + zsh[wave][lane*3+1] + zsh[wave][lane*3+2]) * (1.f/3.f);
        zbsh[wave][lane] = zb;
    }
    __syncthreads();
    float qd = 0.f;
    if (lane < 24){
        #pragma unroll
        for (int e=0;e<24;++e) qd += zbsh[wave][e] * ricci[e*24+lane];
        q[(size_t)p*DDIM + lane] = qd;
    }
    float qs = (lane<24) ? qd*qd : 0.f;
    #pragma unroll
    for (int off=32; off; off>>=1) qs += __shfl_xor(qs,off);
    if (lane == 0) qq[p] = qs;
    const float* Ypr = Yp + (size_t)p*256;
    #pragma unroll
    for (int j=0;j<4;++j){
        int h = lane + 64*j;
        float u = Ypr[h];
        float ph = TWO_PI_F / (1.f + expf(-u));
        float sn, cs; sincosf(ph, &sn, &cs);
        KCbf[(size_t)p*512 + h]       = f2bf(cs);
        KCbf[(size_t)p*512 + 256 + h] = f2bf(sn);
    }
}

// ---------------- centroid top-8 (fp32), global union ----------------
__global__ __launch_bounds__(256) void cent_topk(
    const float* __restrict__ q, const float* __restrict__ qq,
    const float* __restrict__ centroids, const float* __restrict__ centnorm,
    int* __restrict__ sel)
{
    int wave = threadIdx.x >> 6, lane = threadIdx.x & 63;
    int p = blockIdx.x*4 + wave;
    __shared__ float qsh[4][24];
    if (lane < 24) qsh[wave][lane] = q[(size_t)p*DDIM + lane];
    __syncthreads();
    float qv = qq[p];
    float d[4]; int ci[4];
    #pragma unroll
    for (int j=0;j<4;++j){
        int c = lane + 64*j;
        float dot = 0.f;
        #pragma unroll
        for (int e=0;e<24;++e) dot += qsh[wave][e]*centroids[c*24+e];
        d[j] = qv + centnorm[c] - 2.f*dot;
        ci[j] = c;
    }
    for (int k=0;k<8;++k){
        float mv = d[0]; int mi = ci[0];
        #pragma unroll
        for (int j=1;j<4;++j) if (d[j] < mv || (d[j]==mv && ci[j]<mi)){ mv=d[j]; mi=ci[j]; }
        #pragma unroll
        for (int off=32; off; off>>=1){
            float ov = __shfl_xor(mv,off); int oi = __shfl_xor(mi,off);
            if (ov < mv || (ov==mv && oi<mi)){ mv=ov; mi=oi; }
        }
        if ((mi & 63) == lane){
            int j = mi >> 6;
            if (j==0) d[0]=INFINITY; else if (j==1) d[1]=INFINITY;
            else if (j==2) d[2]=INFINITY; else d[3]=INFINITY;
            sel[mi] = 1;
        }
    }
}

__global__ void mask_count(const int* __restrict__ sel, const int* __restrict__ cids,
                           int* __restrict__ maskKey, int* __restrict__ count)
{
    int m = blockIdx.x*256 + threadIdx.x;
    int v = sel[cids[m]];
    maskKey[m] = v;
    int lane = threadIdx.x & 63;
    #pragma unroll
    for (int off=32; off; off>>=1) v += __shfl_xor(v, off);
    if (lane == 0) atomicAdd(count, v);
}

// ---------------- top-32 select (fp32, round-1 numerics) + value/holo read ----------------
__global__ __launch_bounds__(256) void select_read(
    const float* __restrict__ keysT,
    const float* __restrict__ q, const float* __restrict__ qq,
    const float* __restrict__ keynorm, const int* __restrict__ maskKey,
    const int* __restrict__ count, const float* __restrict__ coefp,
    const float* __restrict__ values, const float* __restrict__ hr,
    const float* __restrict__ hi, const float* __restrict__ KF,
    float* __restrict__ vread, ushort* __restrict__ Xcatbf)
{
    const int p = blockIdx.x;
    const int t = threadIdx.x;
    __shared__ float sd[MKEYS];
    __shared__ float q24[24];
    __shared__ float rv[4]; __shared__ int ri[4];
    __shared__ float sv[KTOP]; __shared__ int sidx[KTOP];
    __shared__ float sw[KTOP];
    __shared__ float ssum_sh;
    bool useAll = (*count) < 32;
    float qv = qq[p];
    if (t < 24) q24[t] = q[(size_t)p*DDIM + t];
    __syncthreads();

    {
        float qr[24];
        #pragma unroll
        for (int e=0;e<24;++e) qr[e] = q24[e];
        float acc[16];
        #pragma unroll
        for (int i=0;i<16;++i) acc[i] = 0.f;
        for (int e=0;e<24;++e){
            float qd = qr[e];
            const float* kr = keysT + (size_t)e*MKEYS + t;
            #pragma unroll
            for (int i=0;i<16;++i) acc[i] += qd * kr[256*i];
        }
        #pragma unroll
        for (int i=0;i<16;++i){
            int m = t + 256*i;
            float dd = qv + keynorm[m] - 2.f*acc[i];
            bool ok = useAll || (maskKey[m] != 0);
            sd[m] = ok ? dd : INFINITY;
        }
    }
    __syncthreads();

    float mv = INFINITY; int mi = 0x7fffffff;
    #pragma unroll
    for (int i=0;i<16;++i){
        int m = t + 256*i; float v = sd[m];
        if (v < mv){ mv = v; mi = m; }
    }
    int lane = t & 63, wid = t >> 6;
    for (int k=0;k<KTOP;++k){
        float v = mv; int idx = mi;
        #pragma unroll
        for (int off=32; off; off>>=1){
            float ov = __shfl_xor(v,off); int oi = __shfl_xor(idx,off);
            if (ov < v || (ov==v && oi<idx)){ v=ov; idx=oi; }
        }
        if (lane == 0){ rv[wid] = v; ri[wid] = idx; }
        __syncthreads();
        float gv = rv[0]; int gi = ri[0];
        #pragma unroll
        for (int w=1; w<4; ++w){
            float ov = rv[w]; int oi = ri[w];
            if (ov < gv || (ov==gv && oi<gi)){ gv=ov; gi=oi; }
        }
        if (t == 0){ sv[k] = gv; sidx[k] = gi; }
        if (t == (gi & 255)){
            sd[gi] = INFINITY;
            mv = INFINITY; mi = 0x7fffffff;
            #pragma unroll
            for (int i=0;i<16;++i){ int m = t+256*i; float vv = sd[m]; if (vv < mv){ mv=vv; mi=m; } }
        }
        __syncthreads();
    }

    float coef = *coefp;
    if (t < KTOP) sw[t] = expf(-coef * (sv[t] - sv[0]));
    __syncthreads();
    if (t == 0){
        float s = 0.f;
        #pragma unroll
        for (int k=0;k<KTOP;++k) s += sw[k];
        ssum_sh = 1.f / s;
    }
    __syncthreads();
    float inv = ssum_sh;

    if (t < 72){
        float a = 0.f;
        for (int k=0;k<KTOP;++k) a += sw[k]*values[(size_t)sidx[k]*72 + t];
        vread[(size_t)p*72 + t] = a * inv;
    }
    {
        int h = t;
        float sr = 0.f, si = 0.f;
        for (int k=0;k<KTOP;++k){
            float w = sw[k];
            size_t off = (size_t)sidx[k]*HDIM + h;
            sr += w*hr[off]; si += w*hi[off];
        }
        sr *= inv; si *= inv;
        float Rk = KF[(size_t)p*512 + h], Ik = KF[(size_t)p*512 + 256 + h];
        Xcatbf[(size_t)p*512 + h]       = f2bf(sr*Rk + si*Ik);
        Xcatbf[(size_t)p*512 + 256 + h] = f2bf(si*Rk - sr*Ik);
    }
}

// ---------------- final LN+GELU, in place on d_out ----------------
__global__ __launch_bounds__(256) void ln_gelu_out(float* __restrict__ O)
{
    int p = blockIdx.x; int t = threadIdx.x;
    float4 v = *(float4*)&O[(size_t)p*IN_DIM + t*4];
    float s  = v.x+v.y+v.z+v.w;
    float s2 = v.x*v.x+v.y*v.y+v.z*v.z+v.w*v.w;
    #pragma unroll
    for (int off=32; off; off>>=1){ s += __shfl_xor(s,off); s2 += __shfl_xor(s2,off); }
    __shared__ float as[4], as2[4];
    int lane = t & 63, w = t >> 6;
    if (lane == 0){ as[w] = s; as2[w] = s2; }
    __syncthreads();
    s = as[0]+as[1]+as[2]+as[3];
    s2 = as2[0]+as2[1]+as2[2]+as2[3];
    float mean = s * (1.f/1024.f);
    float var  = s2 * (1.f/1024.f) - mean*mean;
    float rstd = rsqrtf(var + 1e-5f);
    v.x = gelu_f((v.x-mean)*rstd);
    v.y = gelu_f((v.y-mean)*rstd);
    v.z = gelu_f((v.z-mean)*rstd);
    v.w = gelu_f((v.w-mean)*rstd);
    *(float4*)&O[(size_t)p*IN_DIM + t*4] = v;
}

extern "C" void kernel_launch(void* const* d_in, const int* in_sizes, int n_in,
                              void* d_out, int out_size, void* d_ws, size_t ws_size,
                              hipStream_t stream)
{
    const float* x      = (const float*)d_in[0];
    const float* keys   = (const float*)d_in[1];
    const float* values = (const float*)d_in[2];
    const float* W_in   = (const float*)d_in[3];
    const float* b_in   = (const float*)d_in[4];
    const float* ricci  = (const float*)d_in[5];
    const float* fw     = (const float*)d_in[6];
    const float* cent   = (const float*)d_in[7];
    const float* Wk     = (const float*)d_in[8];
    const float* bk     = (const float*)d_in[9];
    const float* ek     = (const float*)d_in[10];
    const float* hr     = (const float*)d_in[11];
    const float* hi     = (const float*)d_in[12];
    const float* Wr     = (const float*)d_in[13];
    const float* brd    = (const float*)d_in[14];
    const float* W_out  = (const float*)d_in[15];
    const float* b_out  = (const float*)d_in[16];
    const int*   cids   = (const int*)d_in[17];
    float* ws  = (float*)d_ws;
    float* out = (float*)d_out;
    int* sel   = (int*)(ws + o_sel);
    int* mask  = (int*)(ws + o_mask);
    int* count = (int*)(ws + o_count);
    ushort* A3     = (ushort*)(ws + o_A3);
    ushort* W2cat  = (ushort*)(ws + o_W2cat);
    ushort* KCbf   = (ushort*)(ws + o_KCbf);
    ushort* TTT    = (ushort*)(ws + o_TTT);
    ushort* Xcatbf = (ushort*)(ws + o_Xcatbf);
    ushort* W2T    = (ushort*)(ws + o_W2T);
    ushort* membf  = (ushort*)(ws + o_membf);
    ushort* WoutT  = (ushort*)(ws + o_WoutT);
    const int NOMASK = 0x7fffffff;

    setup_small<<<1,256,0,stream>>>(fw, cent, ws+o_coef, ws+o_centnorm, sel, count);
    key_setup<<<16,256,0,stream>>>(keys, ws+o_keynorm, ws+o_keysT);
    conv_x2<<<4096,256,0,stream>>>(x, A3);
    conv_W2cat<<<2048,256,0,stream>>>(Wk, W2cat);
    conv_WoutT<<<(IN_DIM*96)/256,256,0,stream>>>(W_out, WoutT);
    build_TTT<<<1024,256,0,stream>>>(ek, TTT);
    build_W2T<<<144,256,0,stream>>>(Wr, W2T);

    // Yq = x @ W_in + b_in  (fp32 VALU, selection-critical, round-1 numerics)
    yq_gemm<<<1024,256,0,stream>>>(x, W_in, b_in, ws+o_Yq);
    // Yp = x @ Wk + bk  (smooth phase path): [xh|xl] @ [wh|wh] = x·wh exactly
    gemm_bf16<<<dim3(4,64),256,0,stream>>>(A3, W2cat, ws+o_Yp, bk, nullptr, nullptr,
                                           P_TOT, 256, 2048, 256, 0, 2048, 2048, 2047);
    post_proj<<<1024,256,0,stream>>>(ws+o_Yq, ws+o_Yp, ricci, ws+o_q, ws+o_qq, KCbf);
    // KF = KC @ TT  (forward FFT + entangle, smooth)
    gemm_bf16<<<dim3(8,64),256,0,stream>>>(KCbf, TTT, ws+o_KF, nullptr, nullptr, nullptr,
                                           P_TOT, 512, 512, 512, 0, 512, 512, NOMASK);
    cent_topk<<<1024,256,0,stream>>>(ws+o_q, ws+o_qq, cent, ws+o_centnorm, sel);
    mask_count<<<16,256,0,stream>>>(sel, cids, mask, count);
    select_read<<<P_TOT,256,0,stream>>>(ws+o_keysT, ws+o_q, ws+o_qq, ws+o_keynorm,
                                        mask, count, ws+o_coef, values, hr, hi, ws+o_KF,
                                        ws+o_vread, Xcatbf);
    // mem = Xcat @ W2 + b_read + vread  -> bf16 (padded to 96 cols)
    gemm_bf16<<<dim3(2,64),256,0,stream>>>(Xcatbf, W2T, nullptr, brd, ws+o_vread, membf,
                                           P_TOT, 72, 512, 72, 96, 512, 512, NOMASK);
    // out = mem @ W_out + b_out
    gemm_bf16<<<dim3(16,64),256,0,stream>>>(membf, WoutT, out, b_out, nullptr, nullptr,
                                            P_TOT, IN_DIM, 96, IN_DIM, 0, 96, 96, NOMASK);
    ln_gelu_out<<<P_TOT,256,0,stream>>>(out);
}

// Round 6
// 454.774 us; speedup vs baseline: 1.2882x; 1.2882x over previous
//
#include <hip/hip_runtime.h>
#include <math.h>

#define P_TOT 4096
#define IN_DIM 1024
#define DDIM 24
#define MKEYS 4096
#define HDIM 256
#define CCENT 256
#define KTOP 32

typedef short bf16x8 __attribute__((ext_vector_type(8)));
typedef float f32x4 __attribute__((ext_vector_type(4)));

// ---- workspace layout (float units) ----
static const size_t o_Yq      = 0;                                   // 4096x72 f32
static const size_t o_Yp      = o_Yq + (size_t)P_TOT*72;             // 4096x256 f32
static const size_t o_q       = o_Yp + (size_t)P_TOT*256;            // 4096x24 f32
static const size_t o_qq      = o_q + (size_t)P_TOT*DDIM;            // 4096 f32
static const size_t o_KF      = o_qq + P_TOT;                        // 4096x512 f32
static const size_t o_keynorm = o_KF + (size_t)P_TOT*512;            // 4096
static const size_t o_centnorm= o_keynorm + MKEYS;                   // 256
static const size_t o_coef    = o_centnorm + CCENT;                  // 64
static const size_t o_vread   = o_coef + 64;                         // 4096x72 f32
static const size_t o_keysT   = o_vread + (size_t)P_TOT*72;          // 24x4096 f32
static const size_t o_sel     = o_keysT + (size_t)DDIM*MKEYS;        // 256 int
static const size_t o_mask    = o_sel + 256;                         // 4096 int
static const size_t o_count   = o_mask + MKEYS;                      // 64 int
static const size_t o_A6      = o_count + 64;                        // 4096x3072 bf16 [x0|x1|x2]
static const size_t o_W6T     = o_A6 + (size_t)P_TOT*3072/2;         // 72x6144 bf16
static const size_t o_W2cat   = o_W6T + (size_t)72*6144/2;           // 256x2048 bf16 [wh|wh]
static const size_t o_KCbf    = o_W2cat + (size_t)256*2048/2;        // 4096x512 bf16
static const size_t o_TTT     = o_KCbf + (size_t)P_TOT*512/2;        // 512x512 bf16
static const size_t o_Xcatbf  = o_TTT + (size_t)512*512/2;           // 4096x512 bf16
static const size_t o_W2T     = o_Xcatbf + (size_t)P_TOT*512/2;      // 72x512 bf16
static const size_t o_membf   = o_W2T + (size_t)72*512/2;            // 4096x96 bf16
static const size_t o_WoutT   = o_membf + (size_t)P_TOT*96/2;        // 1024x96 bf16

__device__ __forceinline__ float gelu_f(float x){
    return 0.5f * x * (1.0f + erff(x * 0.70710678118654752f));
}
__device__ __forceinline__ ushort f2bf(float f){
    union { float f; unsigned u; } a; a.f = f;
    unsigned u = a.u;
    return (ushort)((u + 0x7fffu + ((u >> 16) & 1u)) >> 16);
}
__device__ __forceinline__ float bf2f(ushort b){
    union { unsigned u; float f; } a; a.u = ((unsigned)b) << 16;
    return a.f;
}

#define TWO_PI_F 6.2831853071795864769f
#define STEP_F   0.024543692606170262f   // 2*pi/256

// ---------------- setup kernels ----------------
__global__ void setup_small(const float* __restrict__ fw, const float* __restrict__ cent,
                            float* __restrict__ coefp, float* __restrict__ centnorm,
                            int* __restrict__ sel, int* __restrict__ count)
{
    int t = threadIdx.x;
    if (t == 0){
        float m = fmaxf(fmaxf(fw[0],fw[1]),fmaxf(fw[2],fw[3]));
        float e0=expf(fw[0]-m), e1=expf(fw[1]-m), e2=expf(fw[2]-m), e3=expf(fw[3]-m);
        float s = e0+e1+e2+e3;
        *coefp = (e0 + e1*0.25f + e2*0.0625f + e3*0.015625f) / s;
        *count = 0;
    }
    if (t < CCENT){
        sel[t] = 0;
        float s = 0.f;
        #pragma unroll
        for (int d=0; d<DDIM; ++d){ float v = cent[t*DDIM+d]; s += v*v; }
        centnorm[t] = s;
    }
}

__global__ void key_setup(const float* __restrict__ keys, float* __restrict__ keynorm,
                          float* __restrict__ keysT)
{
    int m = blockIdx.x*256 + threadIdx.x;
    float s = 0.f;
    #pragma unroll
    for (int d=0; d<DDIM; ++d){
        float v = keys[m*DDIM+d]; s += v*v;
        keysT[(size_t)d*MKEYS + m] = v;
    }
    keynorm[m] = s;
}

// x -> triple-split bf16: A6[p] = [x0(1024) | x1(1024) | x2(1024)]
__global__ void conv_x3(const float* __restrict__ x, ushort* __restrict__ A6)
{
    int i = blockIdx.x*256 + threadIdx.x;
    int p = i >> 8, j = (i & 255) * 4;
    float4 v = *(const float4*)&x[(size_t)p*IN_DIM + j];
    ushort4 s0, s1, s2;
    float r;
    s0.x=f2bf(v.x); r=v.x-bf2f(s0.x); s1.x=f2bf(r); s2.x=f2bf(r-bf2f(s1.x));
    s0.y=f2bf(v.y); r=v.y-bf2f(s0.y); s1.y=f2bf(r); s2.y=f2bf(r-bf2f(s1.y));
    s0.z=f2bf(v.z); r=v.z-bf2f(s0.z); s1.z=f2bf(r); s2.z=f2bf(r-bf2f(s1.z));
    s0.w=f2bf(v.w); r=v.w-bf2f(s0.w); s1.w=f2bf(r); s2.w=f2bf(r-bf2f(s1.w));
    *(ushort4*)&A6[(size_t)p*3072 + j]        = s0;
    *(ushort4*)&A6[(size_t)p*3072 + 1024 + j] = s1;
    *(ushort4*)&A6[(size_t)p*3072 + 2048 + j] = s2;
}

// W6T[n][seg*1024+k] : B-side segment pattern [w0,w1,w0,w2,w1,w0]
__global__ void conv_W6(const float* __restrict__ Win, ushort* __restrict__ W6T)
{
    int idx = blockIdx.x*256 + threadIdx.x;    // 72*6144
    if (idx >= 72*6144) return;
    int n = idx / 6144, kp = idx - n*6144;
    int seg = kp >> 10, kk = kp & 1023;
    int sb = (0x012010 >> (seg << 2)) & 0xF;
    float w = Win[kk*72 + n];
    ushort w0 = f2bf(w);
    float r1 = w - bf2f(w0);
    ushort w1 = f2bf(r1);
    ushort w2 = f2bf(r1 - bf2f(w1));
    W6T[idx] = (sb == 0) ? w0 : (sb == 1 ? w1 : w2);
}

// W2cat[n] = [wh(1024) | wh(1024)], n = phase col (Wk col)
__global__ void conv_W2cat(const float* __restrict__ Wk, ushort* __restrict__ W2cat)
{
    int idx = blockIdx.x*256 + threadIdx.x;    // 256*2048
    int n = idx >> 11, k = idx & 2047;
    int kk = k & 1023;
    W2cat[idx] = f2bf(Wk[kk*256 + n]);
}

__global__ void conv_WoutT(const float* __restrict__ Wout, ushort* __restrict__ WoutT)
{
    int idx = blockIdx.x*256 + threadIdx.x;    // 1024*96
    int n = idx / 96, k = idx - n*96;
    float v = (k < 72) ? Wout[(size_t)k*IN_DIM + n] : 0.f;
    WoutT[idx] = f2bf(v);
}

// forward-DFT + entangle folded, transposed bf16: TTT[c][r]
__global__ void build_TTT(const float* __restrict__ ek, ushort* __restrict__ TTT)
{
    int idx = blockIdx.x*256 + threadIdx.x;   // 512*512, idx = c*512 + r
    int c = idx >> 9, r = idx & 511;
    int n = c & 255, h = r & 255;
    float th = (float)((n*h) & 255) * STEP_F - ek[n];
    float sn, cs; sincosf(th, &sn, &cs);
    float v;
    if (r < 256) v = (c < 256) ? cs : -sn;
    else         v = (c < 256) ? sn : cs;
    TTT[idx] = f2bf(v);
}

// inverse-DFT folded into W_read, transposed bf16: W2T[j][k]
__global__ void build_W2T(const float* __restrict__ Wr, ushort* __restrict__ W2T)
{
    __shared__ float tab[256];
    int t = threadIdx.x;
    tab[t] = cosf((float)t * STEP_F);
    __syncthreads();
    int idx = blockIdx.x*256 + t;   // 72*512
    if (idx >= 72*512) return;
    int j = idx >> 9, k = idx & 511;
    int n = k & 255;
    float acc = 0.f;
    for (int h=0; h<256; ++h){
        int xdx = (n*h) & 255;
        float c = tab[xdx], s = tab[(xdx+192) & 255];
        float w1 = Wr[h*72 + j], w2 = Wr[(256+h)*72 + j];
        acc += (k < 256) ? (c*w1 + s*w2) : (c*w2 - s*w1);
    }
    W2T[idx] = f2bf(acc * (1.f/256.f));
}

// ---------------- bf16 MFMA GEMM ----------------
// amode==0: A k-index = (k0+off)&aMask.  amode==1: 6-term split-precision
// pattern: A segs [x0,x0,x1,x0,x1,x2] over K'=6144 (B packed to match).
__global__ __launch_bounds__(256) void gemm_bf16(
    const ushort* __restrict__ A, const ushort* __restrict__ BT,
    float* __restrict__ C, const float* __restrict__ bias,
    const float* __restrict__ addm, ushort* __restrict__ Cbf,
    int M, int N, int Kloop, int Nb, int NbfPad, int lda, int ldb, int aMask,
    int amode)
{
    __shared__ __align__(16) ushort As[64][40];
    __shared__ __align__(16) ushort Bs[64][40];
    const int tid = threadIdx.x;
    const int lane = tid & 63, wid = tid >> 6;
    const int wm = wid >> 1, wn = wid & 1;
    const int m0 = blockIdx.y * 64, n0 = blockIdx.x * 64;
    const int fr = lane & 15, fc = lane >> 4;
    const int srow = tid >> 2, schunk = (tid & 3) * 8;
    f32x4 acc[2][2] = {};
    for (int k0 = 0; k0 < Kloop; k0 += 32){
        int kk = k0 + schunk;
        int ka;
        if (amode) ka = (((0x210100 >> ((kk >> 10) << 2)) & 0xF) << 10) | (kk & 1023);
        else       ka = kk & aMask;
        *(bf16x8*)&As[srow][schunk] =
            *(const bf16x8*)&A[(size_t)(m0 + srow) * lda + ka];
        {
            int n = n0 + srow;
            bf16x8 v = {};
            if (n < Nb) v = *(const bf16x8*)&BT[(size_t)n * ldb + kk];
            *(bf16x8*)&Bs[srow][schunk] = v;
        }
        __syncthreads();
        bf16x8 a0 = *(bf16x8*)&As[wm*32 + fr][fc*8];
        bf16x8 a1 = *(bf16x8*)&As[wm*32 + 16 + fr][fc*8];
        bf16x8 b0 = *(bf16x8*)&Bs[wn*32 + fr][fc*8];
        bf16x8 b1 = *(bf16x8*)&Bs[wn*32 + 16 + fr][fc*8];
        acc[0][0] = __builtin_amdgcn_mfma_f32_16x16x32_bf16(a0, b0, acc[0][0], 0,0,0);
        acc[0][1] = __builtin_amdgcn_mfma_f32_16x16x32_bf16(a0, b1, acc[0][1], 0,0,0);
        acc[1][0] = __builtin_amdgcn_mfma_f32_16x16x32_bf16(a1, b0, acc[1][0], 0,0,0);
        acc[1][1] = __builtin_amdgcn_mfma_f32_16x16x32_bf16(a1, b1, acc[1][1], 0,0,0);
        __syncthreads();
    }
    #pragma unroll
    for (int mi=0; mi<2; ++mi){
        #pragma unroll
        for (int ni=0; ni<2; ++ni){
            #pragma unroll
            for (int rr=0; rr<4; ++rr){
                int gm = m0 + wm*32 + mi*16 + fc*4 + rr;
                int gn = n0 + wn*32 + ni*16 + fr;
                float v = acc[mi][ni][rr];
                if (gn < N){
                    if (bias) v += bias[gn];
                    if (addm) v += addm[(size_t)gm*N + gn];
                    if (C) C[(size_t)gm*N + gn] = v;
                } else v = 0.f;
                if (Cbf && gn < NbfPad)
                    Cbf[(size_t)gm*NbfPad + gn] = f2bf(v);
            }
        }
    }
}

// ---------------- LN+GELU+ricci (from Yq) + phase (from Yp) ----------------
__global__ __launch_bounds__(256) void post_proj(
    const float* __restrict__ Yq, const float* __restrict__ Yp,
    const float* __restrict__ ricci,
    float* __restrict__ q, float* __restrict__ qq, ushort* __restrict__ KCbf)
{
    int wave = threadIdx.x >> 6, lane = threadIdx.x & 63;
    int p = blockIdx.x*4 + wave;
    __shared__ float zsh[4][72];
    __shared__ float zbsh[4][24];
    const float* Yr = Yq + (size_t)p*72;
    float v1 = Yr[lane];
    float v2 = (lane < 8) ? Yr[64+lane] : 0.f;
    float s = v1 + v2, s2 = v1*v1 + v2*v2;
    #pragma unroll
    for (int off=32; off; off>>=1){ s += __shfl_xor(s,off); s2 += __shfl_xor(s2,off); }
    float mean = s * (1.f/72.f);
    float var  = s2 * (1.f/72.f) - mean*mean;
    float rstd = rsqrtf(var + 1e-5f);
    zsh[wave][lane] = gelu_f((v1-mean)*rstd);
    if (lane < 8) zsh[wave][64+lane] = gelu_f((v2-mean)*rstd);
    __syncthreads();
    if (lane < 24){
        float zb = (zsh[wave][lane*3] + zsh[wave][lane*3+1] + zsh[wave][lane*3+2]) * (1.f/3.f);
        zbsh[wave][lane] = zb;
    }
    __syncthreads();
    float qd = 0.f;
    if (lane < 24){
        #pragma unroll
        for (int e=0;e<24;++e) qd += zbsh[wave][e] * ricci[e*24+lane];
        q[(size_t)p*DDIM + lane] = qd;
    }
    float qs = (lane<24) ? qd*qd : 0.f;
    #pragma unroll
    for (int off=32; off; off>>=1) qs += __shfl_xor(qs,off);
    if (lane == 0) qq[p] = qs;
    const float* Ypr = Yp + (size_t)p*256;
    #pragma unroll
    for (int j=0;j<4;++j){
        int h = lane + 64*j;
        float u = Ypr[h];
        float ph = TWO_PI_F / (1.f + expf(-u));
        float sn, cs; sincosf(ph, &sn, &cs);
        KCbf[(size_t)p*512 + h]       = f2bf(cs);
        KCbf[(size_t)p*512 + 256 + h] = f2bf(sn);
    }
}

// ---------------- centroid top-8 (fp32), global union ----------------
__global__ __launch_bounds__(256) void cent_topk(
    const float* __restrict__ q, const float* __restrict__ qq,
    const float* __restrict__ centroids, const float* __restrict__ centnorm,
    int* __restrict__ sel)
{
    int wave = threadIdx.x >> 6, lane = threadIdx.x & 63;
    int p = blockIdx.x*4 + wave;
    __shared__ float qsh[4][24];
    if (lane < 24) qsh[wave][lane] = q[(size_t)p*DDIM + lane];
    __syncthreads();
    float qv = qq[p];
    float d[4]; int ci[4];
    #pragma unroll
    for (int j=0;j<4;++j){
        int c = lane + 64*j;
        float dot = 0.f;
        #pragma unroll
        for (int e=0;e<24;++e) dot += qsh[wave][e]*centroids[c*24+e];
        d[j] = qv + centnorm[c] - 2.f*dot;
        ci[j] = c;
    }
    for (int k=0;k<8;++k){
        float mv = d[0]; int mi = ci[0];
        #pragma unroll
        for (int j=1;j<4;++j) if (d[j] < mv || (d[j]==mv && ci[j]<mi)){ mv=d[j]; mi=ci[j]; }
        #pragma unroll
        for (int off=32; off; off>>=1){
            float ov = __shfl_xor(mv,off); int oi = __shfl_xor(mi,off);
            if (ov < mv || (ov==mv && oi<mi)){ mv=ov; mi=oi; }
        }
        if ((mi & 63) == lane){
            int j = mi >> 6;
            if (j==0) d[0]=INFINITY; else if (j==1) d[1]=INFINITY;
            else if (j==2) d[2]=INFINITY; else d[3]=INFINITY;
            sel[mi] = 1;
        }
    }
}

__global__ void mask_count(const int* __restrict__ sel, const int* __restrict__ cids,
                           int* __restrict__ maskKey, int* __restrict__ count)
{
    int m = blockIdx.x*256 + threadIdx.x;
    int v = sel[cids[m]];
    maskKey[m] = v;
    int lane = threadIdx.x & 63;
    #pragma unroll
    for (int off=32; off; off>>=1) v += __shfl_xor(v, off);
    if (lane == 0) atomicAdd(count, v);
}

// ---------------- top-32 select (fp32) + value/holo read ----------------
__global__ __launch_bounds__(256) void select_read(
    const float* __restrict__ keysT,
    const float* __restrict__ q, const float* __restrict__ qq,
    const float* __restrict__ keynorm, const int* __restrict__ maskKey,
    const int* __restrict__ count, const float* __restrict__ coefp,
    const float* __restrict__ values, const float* __restrict__ hr,
    const float* __restrict__ hi, const float* __restrict__ KF,
    float* __restrict__ vread, ushort* __restrict__ Xcatbf)
{
    const int p = blockIdx.x;
    const int t = threadIdx.x;
    __shared__ float sd[MKEYS];
    __shared__ float q24[24];
    __shared__ float rv[4]; __shared__ int ri[4];
    __shared__ float sv[KTOP]; __shared__ int sidx[KTOP];
    __shared__ float sw[KTOP];
    __shared__ float ssum_sh;
    bool useAll = (*count) < 32;
    float qv = qq[p];
    if (t < 24) q24[t] = q[(size_t)p*DDIM + t];
    __syncthreads();

    {
        float qr[24];
        #pragma unroll
        for (int e=0;e<24;++e) qr[e] = q24[e];
        float acc[16];
        #pragma unroll
        for (int i=0;i<16;++i) acc[i] = 0.f;
        for (int e=0;e<24;++e){
            float qd = qr[e];
            const float* kr = keysT + (size_t)e*MKEYS + t;
            #pragma unroll
            for (int i=0;i<16;++i) acc[i] += qd * kr[256*i];
        }
        #pragma unroll
        for (int i=0;i<16;++i){
            int m = t + 256*i;
            float dd = qv + keynorm[m] - 2.f*acc[i];
            bool ok = useAll || (maskKey[m] != 0);
            sd[m] = ok ? dd : INFINITY;
        }
    }
    __syncthreads();

    float mv = INFINITY; int mi = 0x7fffffff;
    #pragma unroll
    for (int i=0;i<16;++i){
        int m = t + 256*i; float v = sd[m];
        if (v < mv){ mv = v; mi = m; }
    }
    int lane = t & 63, wid = t >> 6;
    for (int k=0;k<KTOP;++k){
        float v = mv; int idx = mi;
        #pragma unroll
        for (int off=32; off; off>>=1){
            float ov = __shfl_xor(v,off); int oi = __shfl_xor(idx,off);
            if (ov < v || (ov==v && oi<idx)){ v=ov; idx=oi; }
        }
        if (lane == 0){ rv[wid] = v; ri[wid] = idx; }
        __syncthreads();
        float gv = rv[0]; int gi = ri[0];
        #pragma unroll
        for (int w=1; w<4; ++w){
            float ov = rv[w]; int oi = ri[w];
            if (ov < gv || (ov==gv && oi<gi)){ gv=ov; gi=oi; }
        }
        if (t == 0){ sv[k] = gv; sidx[k] = gi; }
        if (t == (gi & 255)){
            sd[gi] = INFINITY;
            mv = INFINITY; mi = 0x7fffffff;
            #pragma unroll
            for (int i=0;i<16;++i){ int m = t+256*i; float vv = sd[m]; if (vv < mv){ mv=vv; mi=m; } }
        }
        __syncthreads();
    }

    float coef = *coefp;
    if (t < KTOP) sw[t] = expf(-coef * (sv[t] - sv[0]));
    __syncthreads();
    if (t == 0){
        float s = 0.f;
        #pragma unroll
        for (int k=0;k<KTOP;++k) s += sw[k];
        ssum_sh = 1.f / s;
    }
    __syncthreads();
    float inv = ssum_sh;

    if (t < 72){
        float a = 0.f;
        for (int k=0;k<KTOP;++k) a += sw[k]*values[(size_t)sidx[k]*72 + t];
        vread[(size_t)p*72 + t] = a * inv;
    }
    {
        int h = t;
        float sr = 0.f, si = 0.f;
        for (int k=0;k<KTOP;++k){
            float w = sw[k];
            size_t off = (size_t)sidx[k]*HDIM + h;
            sr += w*hr[off]; si += w*hi[off];
        }
        sr *= inv; si *= inv;
        float Rk = KF[(size_t)p*512 + h], Ik = KF[(size_t)p*512 + 256 + h];
        Xcatbf[(size_t)p*512 + h]       = f2bf(sr*Rk + si*Ik);
        Xcatbf[(size_t)p*512 + 256 + h] = f2bf(si*Rk - sr*Ik);
    }
}

// ---------------- final LN+GELU, in place on d_out ----------------
__global__ __launch_bounds__(256) void ln_gelu_out(float* __restrict__ O)
{
    int p = blockIdx.x; int t = threadIdx.x;
    float4 v = *(float4*)&O[(size_t)p*IN_DIM + t*4];
    float s  = v.x+v.y+v.z+v.w;
    float s2 = v.x*v.x+v.y*v.y+v.z*v.z+v.w*v.w;
    #pragma unroll
    for (int off=32; off; off>>=1){ s += __shfl_xor(s,off); s2 += __shfl_xor(s2,off); }
    __shared__ float as[4], as2[4];
    int lane = t & 63, w = t >> 6;
    if (lane == 0){ as[w] = s; as2[w] = s2; }
    __syncthreads();
    s = as[0]+as[1]+as[2]+as[3];
    s2 = as2[0]+as2[1]+as2[2]+as2[3];
    float mean = s * (1.f/1024.f);
    float var  = s2 * (1.f/1024.f) - mean*mean;
    float rstd = rsqrtf(var + 1e-5f);
    v.x = gelu_f((v.x-mean)*rstd);
    v.y = gelu_f((v.y-mean)*rstd);
    v.z = gelu_f((v.z-mean)*rstd);
    v.w = gelu_f((v.w-mean)*rstd);
    *(float4*)&O[(size_t)p*IN_DIM + t*4] = v;
}

extern "C" void kernel_launch(void* const* d_in, const int* in_sizes, int n_in,
                              void* d_out, int out_size, void* d_ws, size_t ws_size,
                              hipStream_t stream)
{
    const float* x      = (const float*)d_in[0];
    const float* keys   = (const float*)d_in[1];
    const float* values = (const float*)d_in[2];
    const float* W_in   = (const float*)d_in[3];
    const float* b_in   = (const float*)d_in[4];
    const float* ricci  = (const float*)d_in[5];
    const float* fw     = (const float*)d_in[6];
    const float* cent   = (const float*)d_in[7];
    const float* Wk     = (const float*)d_in[8];
    const float* bk     = (const float*)d_in[9];
    const float* ek     = (const float*)d_in[10];
    const float* hr     = (const float*)d_in[11];
    const float* hi     = (const float*)d_in[12];
    const float* Wr     = (const float*)d_in[13];
    const float* brd    = (const float*)d_in[14];
    const float* W_out  = (const float*)d_in[15];
    const float* b_out  = (const float*)d_in[16];
    const int*   cids   = (const int*)d_in[17];
    float* ws  = (float*)d_ws;
    float* out = (float*)d_out;
    int* sel   = (int*)(ws + o_sel);
    int* mask  = (int*)(ws + o_mask);
    int* count = (int*)(ws + o_count);
    ushort* A6     = (ushort*)(ws + o_A6);
    ushort* W6T    = (ushort*)(ws + o_W6T);
    ushort* W2cat  = (ushort*)(ws + o_W2cat);
    ushort* KCbf   = (ushort*)(ws + o_KCbf);
    ushort* TTT    = (ushort*)(ws + o_TTT);
    ushort* Xcatbf = (ushort*)(ws + o_Xcatbf);
    ushort* W2T    = (ushort*)(ws + o_W2T);
    ushort* membf  = (ushort*)(ws + o_membf);
    ushort* WoutT  = (ushort*)(ws + o_WoutT);
    const int NOMASK = 0x7fffffff;

    setup_small<<<1,256,0,stream>>>(fw, cent, ws+o_coef, ws+o_centnorm, sel, count);
    key_setup<<<16,256,0,stream>>>(keys, ws+o_keynorm, ws+o_keysT);
    conv_x3<<<4096,256,0,stream>>>(x, A6);
    conv_W6<<<(72*6144+255)/256,256,0,stream>>>(W_in, W6T);
    conv_W2cat<<<2048,256,0,stream>>>(Wk, W2cat);
    conv_WoutT<<<(IN_DIM*96)/256,256,0,stream>>>(W_out, WoutT);
    build_TTT<<<1024,256,0,stream>>>(ek, TTT);
    build_W2T<<<144,256,0,stream>>>(Wr, W2T);

    // Yq = x @ W_in + b_in : 6-term bf16 split MFMA == fp32-accurate
    gemm_bf16<<<dim3(2,64),256,0,stream>>>(A6, W6T, ws+o_Yq, b_in, nullptr, nullptr,
                                           P_TOT, 72, 6144, 72, 0, 3072, 6144, NOMASK, 1);
    // Yp = x @ Wk + bk (smooth phase path): [x0|x1] @ [wh|wh]
    gemm_bf16<<<dim3(4,64),256,0,stream>>>(A6, W2cat, ws+o_Yp, bk, nullptr, nullptr,
                                           P_TOT, 256, 2048, 256, 0, 3072, 2048, NOMASK, 0);
    post_proj<<<1024,256,0,stream>>>(ws+o_Yq, ws+o_Yp, ricci, ws+o_q, ws+o_qq, KCbf);
    // KF = KC @ TT  (forward FFT + entangle, smooth)
    gemm_bf16<<<dim3(8,64),256,0,stream>>>(KCbf, TTT, ws+o_KF, nullptr, nullptr, nullptr,
                                           P_TOT, 512, 512, 512, 0, 512, 512, NOMASK, 0);
    cent_topk<<<1024,256,0,stream>>>(ws+o_q, ws+o_qq, cent, ws+o_centnorm, sel);
    mask_count<<<16,256,0,stream>>>(sel, cids, mask, count);
    select_read<<<P_TOT,256,0,stream>>>(ws+o_keysT, ws+o_q, ws+o_qq, ws+o_keynorm,
                                        mask, count, ws+o_coef, values, hr, hi, ws+o_KF,
                                        ws+o_vread, Xcatbf);
    // mem = Xcat @ W2 + b_read + vread  -> bf16 (padded to 96 cols)
    gemm_bf16<<<dim3(2,64),256,0,stream>>>(Xcatbf, W2T, nullptr, brd, ws+o_vread, membf,
                                           P_TOT, 72, 512, 72, 96, 512, 512, NOMASK, 0);
    // out = mem @ W_out + b_out
    gemm_bf16<<<dim3(16,64),256,0,stream>>>(membf, WoutT, out, b_out, nullptr, nullptr,
                                            P_TOT, IN_DIM, 96, IN_DIM, 0, 96, 96, NOMASK, 0);
    ln_gelu_out<<<P_TOT,256,0,stream>>>(out);
}